// Round 11
// baseline (220.262 us; speedup 1.0000x reference)
//
#include <hip/hip_runtime.h>
#include <hip/hip_bf16.h>
#include <cstdint>
#include <cstddef>

// ---------- types ----------
typedef __attribute__((ext_vector_type(4))) float f32x4;
typedef __attribute__((ext_vector_type(8))) short s16x8;
typedef __attribute__((ext_vector_type(4))) unsigned short u16x4;

__device__ __forceinline__ unsigned short f2bf(float f) {
    union { float f; unsigned u; } v; v.f = f;
    unsigned u = v.u;
    u += 0x7fffu + ((u >> 16) & 1u);      // round-to-nearest-even
    return (unsigned short)(u >> 16);
}
__device__ __forceinline__ float lo_f(unsigned v) {   // low bf16 -> f32 (exact)
    union { unsigned u; float f; } w; w.u = v << 16; return w.f;
}
__device__ __forceinline__ float hi_f(unsigned v) {   // high bf16 -> f32 (exact)
    union { unsigned u; float f; } w; w.u = v & 0xffff0000u; return w.f;
}

// =====================================================================
// Network is LINEAR: out_pre = pooled @ Wbig + bbig,
//   Wbig = W1 @ W2 @ [Wc|Wr],  bbig = ((b1@W2)+b2)@[Wc|Wr] + [bc|br].
// Round-11 = round-10 with the nontemporal builtins applied to clang
// ext_vector types (HIP_vector_type is rejected by the builtin).
// Mechanism under test: NT streaming keeps fmT (4.3MB) L2-resident while
// the 411MB W1 stream flows past it in the same dispatch.
// pooled k' ordering: pooled[n][bin*512+c] <-> W1 row (c*49+bin).
// =====================================================================

// ---------- A. prep_all: featmap transpose (blocks 0..2111) + WcatT (2112..2367) ----
__global__ __launch_bounds__(256) void prep_all(
        const float* __restrict__ fm, unsigned short* __restrict__ fmT,
        const float* __restrict__ Wc, const float* __restrict__ Wr,
        unsigned short* __restrict__ WcatT) {
    const int bid = blockIdx.x, t = threadIdx.x;
    if (bid < 2112) {
        __shared__ float tile[32][33];
        int p0 = (bid % 132) * 32, c0 = (bid / 132) * 32;
        int tx = t & 31, ty = t >> 5;
        #pragma unroll
        for (int yy = ty; yy < 32; yy += 8) {
            int p = p0 + tx;
            if (p < 4200) tile[yy][tx] = fm[(size_t)(c0 + yy) * 4200 + p];
        }
        __syncthreads();
        #pragma unroll
        for (int yy = ty; yy < 32; yy += 8) {
            int p = p0 + yy;
            if (p < 4200) fmT[(size_t)p * 512 + c0 + tx] = f2bf(tile[tx][yy]);
        }
    } else {
        int idx = (bid - 2112) * 256 + t;        // 0..65535
        int i = idx >> 4, j = idx & 15;
        float v = (j < 3) ? Wc[i * 3 + j] : (j < 15) ? Wr[i * 12 + (j - 3)] : 0.f;
        WcatT[(size_t)j * 4096 + i] = f2bf(v);
    }
}

// ---------- skinny MFMA body (LDS-free, barrier-free) ----------
// wave = 16 rows x 16 cols; A from global f32 (full 128B line per row per
// step) cvt to bf16 in-reg; B = tiny bf16 [16][4096] (L2-resident, cached).
// NT: A loads + partial stores nontemporal (stream once, keep L2 clean).
template<bool NT>
__device__ __forceinline__ void skinny_body(
        const float* __restrict__ A, const unsigned short* __restrict__ BT,
        float* __restrict__ partial, int R, int kchunk,
        int bx, int ky, int t) {
    const int lane = t & 63, wave = t >> 6;
    const int r0 = bx * 128 + wave * 16;
    const int k0 = ky * kchunk;
    const int lr = lane & 15, lks = lane >> 4;
    const int steps = kchunk >> 5;
    const float* ap = A + (size_t)(r0 + lr) * 4096 + k0 + lks * 8;
    const unsigned short* bp = BT + (size_t)lr * 4096 + k0 + lks * 8;
    f32x4 acc = {0.f, 0.f, 0.f, 0.f};
    for (int s = 0; s < steps; ++s) {
        f32x4 f0, f1;
        if (NT) {
            f0 = __builtin_nontemporal_load((const f32x4*)(ap + s * 32));
            f1 = __builtin_nontemporal_load((const f32x4*)(ap + s * 32 + 4));
        } else {
            f0 = *(const f32x4*)(ap + s * 32);
            f1 = *(const f32x4*)(ap + s * 32 + 4);
        }
        s16x8 b = *(const s16x8*)(bp + s * 32);
        union { unsigned short us[8]; s16x8 v; } a;
        a.us[0] = f2bf(f0.x); a.us[1] = f2bf(f0.y);
        a.us[2] = f2bf(f0.z); a.us[3] = f2bf(f0.w);
        a.us[4] = f2bf(f1.x); a.us[5] = f2bf(f1.y);
        a.us[6] = f2bf(f1.z); a.us[7] = f2bf(f1.w);
        acc = __builtin_amdgcn_mfma_f32_16x16x32_bf16(a.v, b, acc, 0, 0, 0);
    }
    const int row = r0 + (lane >> 4) * 4;
    float* op = partial + ((size_t)ky * R + row) * 16 + lr;
    #pragma unroll
    for (int q = 0; q < 4; ++q) {
        if (NT) __builtin_nontemporal_store(acc[q], op + q * 16);
        else    op[q * 16] = acc[q];
    }
}

// ---------- B. skinny W2: partial1[8][4096][16] = W2 @ WcatT^T ----------
__global__ __launch_bounds__(512) void skinny_w2(
        const float* __restrict__ W2, const unsigned short* __restrict__ WcatT,
        float* __restrict__ partial1) {
    skinny_body<false>(W2, WcatT, partial1, 4096, 512, blockIdx.x, blockIdx.y, threadIdx.x);
}

// ---------- C. reduce partial1 -> Wf16 f32 + WfT bf16; block 256: bfv ----------
__global__ __launch_bounds__(256) void reduce_wf(
        const float* __restrict__ partial1, const float* __restrict__ b2,
        const float* __restrict__ Wc, const float* __restrict__ Wr,
        const float* __restrict__ bc, const float* __restrict__ br,
        float* __restrict__ Wf16, unsigned short* __restrict__ WfT,
        float* __restrict__ bfv) {
    const int t = threadIdx.x;
    if (blockIdx.x < 256) {
        int idx = blockIdx.x * 256 + t;          // over 65536
        float s = 0.f;
        #pragma unroll
        for (int sp = 0; sp < 8; ++sp) s += partial1[sp * 65536 + idx];
        Wf16[idx] = s;
        int i = idx >> 4, j = idx & 15;
        WfT[(size_t)j * 4096 + i] = f2bf(s);     // row 15 stays zero
    } else {
        float acc[15];
        #pragma unroll
        for (int j = 0; j < 15; ++j) acc[j] = 0.f;
        for (int i = t; i < 4096; i += 256) {
            float bv = b2[i];
            #pragma unroll
            for (int j = 0; j < 15; ++j)
                acc[j] += bv * ((j < 3) ? Wc[i * 3 + j] : Wr[i * 12 + (j - 3)]);
        }
        const int lane = t & 63, wv = t >> 6;
        __shared__ float red[4][15];
        #pragma unroll
        for (int j = 0; j < 15; ++j) {
            float x = acc[j];
            #pragma unroll
            for (int off = 32; off >= 1; off >>= 1) x += __shfl_xor(x, off, 64);
            if (lane == 0) red[wv][j] = x;
        }
        __syncthreads();
        if (t < 15)
            bfv[t] = red[0][t] + red[1][t] + red[2][t] + red[3][t]
                   + ((t < 3) ? bc[t] : br[t - 3]);
    }
}

// ---------- D. megaB: pool (1024 virtual blocks) + skinny W1 (784), 3:4 mix ----------
#define PB(NH, NW) { \
    uint2 v[NH * NW]; \
    _Pragma("unroll") for (int r = 0; r < NH; ++r) \
        _Pragma("unroll") for (int s = 0; s < NW; ++s) \
            v[r * NW + s] = *(const uint2*)(base + ho[r] + wo[s]); \
    float a0 = lo_f(v[0].x), a1 = hi_f(v[0].x); \
    float a2 = lo_f(v[0].y), a3 = hi_f(v[0].y); \
    _Pragma("unroll") for (int q = 1; q < NH * NW; ++q) { \
        a0 = fmaxf(a0, lo_f(v[q].x)); a1 = fmaxf(a1, hi_f(v[q].x)); \
        a2 = fmaxf(a2, lo_f(v[q].y)); a3 = fmaxf(a3, hi_f(v[q].y)); } \
    m0 = a0; m1 = a1; m2 = a2; m3 = a3; } break;

__global__ __launch_bounds__(512) void megaB(
        const unsigned short* __restrict__ fmT, const int* __restrict__ roi,
        unsigned short* __restrict__ pooled,
        const float* __restrict__ W1, const unsigned short* __restrict__ WfT,
        float* __restrict__ partial2) {
    const int g7 = blockIdx.x / 7, r7 = blockIdx.x % 7;
    const int t = threadIdx.x;
    if (r7 < 3) {
        // ---- skinny W1 block (nontemporal stream: keep L2 for fmT) ----
        const int sb = g7 * 3 + r7;
        if (sb >= 784) return;
        const int ky = sb / 196, bx = sb % 196;
        skinny_body<true>(W1, WfT, partial2, 25088, 1024, bx, ky, t);
    } else {
        // ---- pool block (one ROI) ----
        const int n = g7 * 4 + (r7 - 3);
        if (n >= 1024) return;
        __shared__ int hoff[7][5], woff[7][5], hcnt[7], wcnt[7];
        if (t == 0) {
            int x0 = roi[n*4+0] / 16, y0 = roi[n*4+1] / 16;
            int x1 = roi[n*4+2] / 16, y1 = roi[n*4+3] / 16;
            if (x1 - x0 <= 1) { if (x1 < 84) x1 += 1; else x0 -= 1; }
            if (y1 - y0 <= 1) { if (y1 < 50) y1 += 1; else y0 -= 1; }
            int xs = min(max(x0, 0), 84), xe = min(max(x1, 0), 84);
            int ys = min(max(y0, 0), 50), ye = min(max(y1, 0), 50);
            int Lx = xe - xs, Ly = ye - ys;
            #pragma unroll
            for (int i = 0; i < 7; ++i) {
                int b0 = ys + (i * Ly) / 7, b1 = ys + ((i + 1) * Ly + 6) / 7;
                hcnt[i] = min(b1, b0 + 5) - b0;
                int c0 = xs + (i * Lx) / 7, c1 = xs + ((i + 1) * Lx + 6) / 7;
                wcnt[i] = min(c1, c0 + 5) - c0;
                #pragma unroll
                for (int q = 0; q < 5; ++q) {
                    hoff[i][q] = (b0 + q) * 43008;
                    woff[i][q] = (c0 + q) * 512;
                }
            }
        }
        __syncthreads();
        const int g = t >> 7;                 // 4 bin groups
        const int c4 = (t & 127) * 4;
        const unsigned short* base = fmT + c4;
        unsigned short* orow = pooled + (size_t)n * 25088;
        for (int bp = 0; bp < 13; ++bp) {
            int bin = bp * 4 + g;
            if (bin < 49) {
                int bi = bin / 7, bj = bin - bi * 7;
                int ho[5], wo[5];
                #pragma unroll
                for (int q = 0; q < 5; ++q) { ho[q] = hoff[bi][q]; wo[q] = woff[bj][q]; }
                int nh = hcnt[bi], nw = wcnt[bj];
                float m0, m1, m2, m3;
                switch ((nh - 1) * 5 + (nw - 1)) {
                    case  0: PB(1,1)  case  1: PB(1,2)  case  2: PB(1,3)
                    case  3: PB(1,4)  case  4: PB(1,5)
                    case  5: PB(2,1)  case  6: PB(2,2)  case  7: PB(2,3)
                    case  8: PB(2,4)  case  9: PB(2,5)
                    case 10: PB(3,1)  case 11: PB(3,2)  case 12: PB(3,3)
                    case 13: PB(3,4)  case 14: PB(3,5)
                    case 15: PB(4,1)  case 16: PB(4,2)  case 17: PB(4,3)
                    case 18: PB(4,4)  case 19: PB(4,5)
                    case 20: PB(5,1)  case 21: PB(5,2)  case 22: PB(5,3)
                    case 23: PB(5,4)  case 24: PB(5,5)
                    default: m0 = m1 = m2 = m3 = 0.f; break;
                }
                u16x4 o;
                o.x = f2bf(m0); o.y = f2bf(m1); o.z = f2bf(m2); o.w = f2bf(m3);
                __builtin_nontemporal_store(o, (u16x4*)(orow + bin * 512 + c4));
            }
        }
    }
}

// ---------- E. reduce partial2 (r-order, 4 splits) -> WbigT bf16 (k'-permuted);
//             block 98 computes bbig ----------
__global__ __launch_bounds__(256) void reduce_wbig(
        const float* __restrict__ partial2, const float* __restrict__ Wf16,
        const float* __restrict__ bfv, const float* __restrict__ b1,
        unsigned short* __restrict__ WbigT, float* __restrict__ bbig) {
    const int t = threadIdx.x;
    if (blockIdx.x < 98) {
        const int r = blockIdx.x * 256 + t;      // W1 row (linear)
        float sj[16];
        #pragma unroll
        for (int j = 0; j < 16; ++j) sj[j] = 0.f;
        #pragma unroll
        for (int sp = 0; sp < 4; ++sp) {
            const float4* pp = (const float4*)(partial2 + ((size_t)sp * 25088 + r) * 16);
            float4 a = pp[0], b = pp[1], c = pp[2], d = pp[3];
            sj[0] += a.x; sj[1] += a.y; sj[2]  += a.z; sj[3]  += a.w;
            sj[4] += b.x; sj[5] += b.y; sj[6]  += b.z; sj[7]  += b.w;
            sj[8] += c.x; sj[9] += c.y; sj[10] += c.z; sj[11] += c.w;
            sj[12] += d.x; sj[13] += d.y; sj[14] += d.z; sj[15] += d.w;
        }
        const int c = r / 49, bin = r - c * 49;
        const int p = bin * 512 + c;             // k' index
        #pragma unroll
        for (int j = 0; j < 16; ++j)
            WbigT[(size_t)j * 25088 + p] = f2bf(sj[j]);
    } else {
        float acc[15];
        #pragma unroll
        for (int j = 0; j < 15; ++j) acc[j] = 0.f;
        for (int i = t; i < 4096; i += 256) {
            float bv = b1[i];
            #pragma unroll
            for (int j = 0; j < 15; ++j) acc[j] += bv * Wf16[i * 16 + j];
        }
        const int lane = t & 63, wv = t >> 6;
        __shared__ float red[4][15];
        #pragma unroll
        for (int j = 0; j < 15; ++j) {
            float x = acc[j];
            #pragma unroll
            for (int off = 32; off >= 1; off >>= 1) x += __shfl_xor(x, off, 64);
            if (lane == 0) red[wv][j] = x;
        }
        __syncthreads();
        if (t < 16) {
            float s = 0.f;
            if (t < 15)
                s = red[0][t] + red[1][t] + red[2][t] + red[3][t] + bfv[t];
            bbig[t] = s;
        }
    }
}

// ---------- F. final GEMM: pooled @ WbigT^T -> partialG[8][1024][16] ----------
__global__ __launch_bounds__(256) void final_gemm(
        const unsigned short* __restrict__ pooled,
        const unsigned short* __restrict__ WbigT,
        float* __restrict__ partialG) {
    const int t = threadIdx.x, lane = t & 63, wave = t >> 6;
    const int m0 = blockIdx.x * 16, kz = blockIdx.y;
    const int lr = lane & 15, lks = lane >> 4;
    f32x4 acc = {0.f, 0.f, 0.f, 0.f};
    const unsigned short* arow = pooled + (size_t)(m0 + lr) * 25088 + kz * 3136 + lks * 8;
    const unsigned short* brow = WbigT + (size_t)lr * 25088 + kz * 3136 + lks * 8;
    for (int s = wave; s < 98; s += 4) {
        s16x8 a = __builtin_nontemporal_load((const s16x8*)(arow + s * 32));
        s16x8 b = *(const s16x8*)(brow + s * 32);
        acc = __builtin_amdgcn_mfma_f32_16x16x32_bf16(a, b, acc, 0, 0, 0);
    }
    __shared__ float red[4][64][4];
    #pragma unroll
    for (int r = 0; r < 4; ++r) red[wave][lane][r] = acc[r];
    __syncthreads();
    if (wave == 0) {
        #pragma unroll
        for (int r = 0; r < 4; ++r) {
            float s = red[0][lane][r] + red[1][lane][r] + red[2][lane][r] + red[3][lane][r];
            int row = m0 + (lane >> 4) * 4 + r;
            partialG[((size_t)kz * 1024 + row) * 16 + (lane & 15)] = s;
        }
    }
}

// ---------- G. finalize: sum 8 partials + bbig, softmax(3), write out ----------
__global__ __launch_bounds__(256) void finalize_kernel(
        const float* __restrict__ partialG, const float* __restrict__ bbig,
        float* __restrict__ out) {
    const int m = blockIdx.x * 256 + threadIdx.x;   // 0..1023
    float v[15];
    #pragma unroll
    for (int j = 0; j < 15; ++j) v[j] = bbig[j];
    for (int kz = 0; kz < 8; ++kz) {
        const float* p = partialG + ((size_t)kz * 1024 + m) * 16;
        #pragma unroll
        for (int j = 0; j < 15; ++j) v[j] += p[j];
    }
    float mx = fmaxf(v[0], fmaxf(v[1], v[2]));
    float e0 = expf(v[0] - mx), e1 = expf(v[1] - mx), e2 = expf(v[2] - mx);
    float inv = 1.f / (e0 + e1 + e2);
    out[m * 3 + 0] = e0 * inv;
    out[m * 3 + 1] = e1 * inv;
    out[m * 3 + 2] = e2 * inv;
    #pragma unroll
    for (int j = 3; j < 15; ++j) out[3072 + m * 12 + (j - 3)] = v[j];
}

// ---------- launch ----------
extern "C" void kernel_launch(void* const* d_in, const int* in_sizes, int n_in,
                              void* d_out, int out_size, void* d_ws, size_t ws_size,
                              hipStream_t stream) {
    const float* featmap = (const float*)d_in[0];
    const int*   roi     = (const int*)d_in[1];
    const float* W1      = (const float*)d_in[2];
    const float* b1      = (const float*)d_in[3];
    const float* W2      = (const float*)d_in[4];
    const float* b2      = (const float*)d_in[5];
    const float* Wc      = (const float*)d_in[6];
    const float* bc      = (const float*)d_in[7];
    const float* Wr      = (const float*)d_in[8];
    const float* br      = (const float*)d_in[9];
    float* out = (float*)d_out;

    // workspace layout (bytes, 16-aligned)
    char* ws = (char*)d_ws;
    unsigned short* pooled   = (unsigned short*)(ws);                // 51,380,224  [1024][25088] bf16 (k')
    unsigned short* fmT      = (unsigned short*)(ws + 51380224);     //  4,300,800  [4200][512] bf16
    unsigned short* WcatT    = (unsigned short*)(ws + 55681024);     //    131,072  [16][4096] bf16
    unsigned short* WfT      = (unsigned short*)(ws + 55812096);     //    131,072  [16][4096] bf16
    float*          Wf16     = (float*)        (ws + 55943168);      //    262,144  [4096][16] f32
    float*          bfv      = (float*)        (ws + 56205312);      //         64
    float*          bbig     = (float*)        (ws + 56205376);      //         64  [16]
    float*          partial1 = (float*)        (ws + 56205440);      //  4,194,304  [8][4096][16] f32
    float*          partial2 = (float*)        (ws + 60399744);      //  6,422,528  [4][25088][16] f32 (r-order)
    unsigned short* WbigT    = (unsigned short*)(ws + 66822272);     //    802,816  [16][25088] bf16 (k'-order)
    float*          partialG = (float*)        (ws + 67625088);      //    524,288  [8][1024][16] f32

    prep_all<<<2368, 256, 0, stream>>>(featmap, fmT, Wc, Wr, WcatT);
    skinny_w2<<<dim3(32, 8), 512, 0, stream>>>(W2, WcatT, partial1);
    reduce_wf<<<257, 256, 0, stream>>>(partial1, b2, Wc, Wr, bc, br, Wf16, WfT, bfv);
    megaB<<<1834, 512, 0, stream>>>(fmT, roi, pooled, W1, WfT, partial2);
    reduce_wbig<<<99, 256, 0, stream>>>(partial2, Wf16, bfv, b1, WbigT, bbig);
    final_gemm<<<dim3(64, 8), 256, 0, stream>>>(pooled, WbigT, partialG);
    finalize_kernel<<<4, 256, 0, stream>>>(partialG, bbig, out);
}

// Round 12
// 213.806 us; speedup vs baseline: 1.0302x; 1.0302x over previous
//
#include <hip/hip_runtime.h>
#include <hip/hip_bf16.h>
#include <cstdint>
#include <cstddef>

// ---------- types ----------
typedef __attribute__((ext_vector_type(4))) float f32x4;
typedef __attribute__((ext_vector_type(8))) short s16x8;
typedef __attribute__((ext_vector_type(4))) unsigned short u16x4;

__device__ __forceinline__ unsigned short f2bf(float f) {
    union { float f; unsigned u; } v; v.f = f;
    unsigned u = v.u;
    u += 0x7fffu + ((u >> 16) & 1u);      // round-to-nearest-even
    return (unsigned short)(u >> 16);
}
__device__ __forceinline__ float lo_f(unsigned v) {   // low bf16 -> f32 (exact)
    union { unsigned u; float f; } w; w.u = v << 16; return w.f;
}
__device__ __forceinline__ float hi_f(unsigned v) {   // high bf16 -> f32 (exact)
    union { unsigned u; float f; } w; w.u = v & 0xffff0000u; return w.f;
}

// =====================================================================
// Network is LINEAR: out_pre = pooled @ Wbig + bbig,
//   Wbig = W1 @ W2 @ [Wc|Wr],  bbig = ((b1@W2)+b2)@[Wc|Wr] + [bc|br].
// Round-12: (a) W1 stream split into 1568 blocks (ky=8, kchunk=512) to
// kill the CU-tail imbalance (was 784 -> 3.06/CU, 25% tail quantization);
// (b) featmap transpose fused into the W2-stream dispatch (independent).
// pooled k' ordering: pooled[n][bin*512+c] <-> W1 row (c*49+bin).
// =====================================================================

// ---------- 1. prep_wcat: WcatT bf16 [16][4096] = [Wc|Wr|0]^T ----------
__global__ __launch_bounds__(256) void prep_wcat(
        const float* __restrict__ Wc, const float* __restrict__ Wr,
        unsigned short* __restrict__ WcatT) {
    int idx = blockIdx.x * 256 + threadIdx.x;    // 0..65535
    int i = idx >> 4, j = idx & 15;
    float v = (j < 3) ? Wc[i * 3 + j] : (j < 15) ? Wr[i * 12 + (j - 3)] : 0.f;
    WcatT[(size_t)j * 4096 + i] = f2bf(v);
}

// ---------- skinny MFMA body (LDS-free, barrier-free) ----------
// wave = 16 rows x 16 cols; A from global f32 (full 128B line per row per
// step) cvt to bf16 in-reg; B = tiny bf16 [16][4096] (L2-resident).
template<bool NT>
__device__ __forceinline__ void skinny_body(
        const float* __restrict__ A, const unsigned short* __restrict__ BT,
        float* __restrict__ partial, int R, int kchunk,
        int bx, int ky, int t) {
    const int lane = t & 63, wave = t >> 6;
    const int r0 = bx * 128 + wave * 16;
    const int k0 = ky * kchunk;
    const int lr = lane & 15, lks = lane >> 4;
    const int steps = kchunk >> 5;
    const float* ap = A + (size_t)(r0 + lr) * 4096 + k0 + lks * 8;
    const unsigned short* bp = BT + (size_t)lr * 4096 + k0 + lks * 8;
    f32x4 acc = {0.f, 0.f, 0.f, 0.f};
    for (int s = 0; s < steps; ++s) {
        f32x4 f0, f1;
        if (NT) {
            f0 = __builtin_nontemporal_load((const f32x4*)(ap + s * 32));
            f1 = __builtin_nontemporal_load((const f32x4*)(ap + s * 32 + 4));
        } else {
            f0 = *(const f32x4*)(ap + s * 32);
            f1 = *(const f32x4*)(ap + s * 32 + 4);
        }
        s16x8 b = *(const s16x8*)(bp + s * 32);
        union { unsigned short us[8]; s16x8 v; } a;
        a.us[0] = f2bf(f0.x); a.us[1] = f2bf(f0.y);
        a.us[2] = f2bf(f0.z); a.us[3] = f2bf(f0.w);
        a.us[4] = f2bf(f1.x); a.us[5] = f2bf(f1.y);
        a.us[6] = f2bf(f1.z); a.us[7] = f2bf(f1.w);
        acc = __builtin_amdgcn_mfma_f32_16x16x32_bf16(a.v, b, acc, 0, 0, 0);
    }
    const int row = r0 + (lane >> 4) * 4;
    float* op = partial + ((size_t)ky * R + row) * 16 + lr;
    #pragma unroll
    for (int q = 0; q < 4; ++q) {
        if (NT) __builtin_nontemporal_store(acc[q], op + q * 16);
        else    op[q * 16] = acc[q];
    }
}

// ---------- 2. prepA: featmap transpose (1056 units x 2 tiles) ∥ skinny W2 (256) ----
// 512-thr blocks, interleaved 4:1 so the L2-light transpose hides under the
// 67MB W2 HBM stream.
__global__ __launch_bounds__(512) void prepA(
        const float* __restrict__ fm, unsigned short* __restrict__ fmT,
        const float* __restrict__ W2, const unsigned short* __restrict__ WcatT,
        float* __restrict__ partial1) {
    const int g5 = blockIdx.x / 5, r5 = blockIdx.x % 5;
    const int t = threadIdx.x;
    if (r5 < 4) {
        const int unit = g5 * 4 + r5;            // 0..1055
        if (unit >= 1056) return;
        __shared__ float tile[2][32][33];
        const int sub = t >> 8, tt = t & 255;
        const int tid = unit * 2 + sub;          // 0..2111
        const int p0 = (tid % 132) * 32, c0 = (tid / 132) * 32;
        const int tx = tt & 31, ty = tt >> 5;
        #pragma unroll
        for (int yy = ty; yy < 32; yy += 8) {
            int p = p0 + tx;
            if (p < 4200) tile[sub][yy][tx] = fm[(size_t)(c0 + yy) * 4200 + p];
        }
        __syncthreads();
        #pragma unroll
        for (int yy = ty; yy < 32; yy += 8) {
            int p = p0 + yy;
            if (p < 4200) fmT[(size_t)p * 512 + c0 + tx] = f2bf(tile[sub][tx][yy]);
        }
    } else {
        const int v = g5;                        // 0..255
        if (v >= 256) return;
        skinny_body<false>(W2, WcatT, partial1, 4096, 512, v & 31, v >> 5, t);
    }
}

// ---------- 3. reduce partial1 -> Wf16 f32 + WfT bf16; block 256: bfv ----------
__global__ __launch_bounds__(256) void reduce_wf(
        const float* __restrict__ partial1, const float* __restrict__ b2,
        const float* __restrict__ Wc, const float* __restrict__ Wr,
        const float* __restrict__ bc, const float* __restrict__ br,
        float* __restrict__ Wf16, unsigned short* __restrict__ WfT,
        float* __restrict__ bfv) {
    const int t = threadIdx.x;
    if (blockIdx.x < 256) {
        int idx = blockIdx.x * 256 + t;          // over 65536
        float s = 0.f;
        #pragma unroll
        for (int sp = 0; sp < 8; ++sp) s += partial1[sp * 65536 + idx];
        Wf16[idx] = s;
        int i = idx >> 4, j = idx & 15;
        WfT[(size_t)j * 4096 + i] = f2bf(s);     // row 15 stays zero
    } else {
        float acc[15];
        #pragma unroll
        for (int j = 0; j < 15; ++j) acc[j] = 0.f;
        for (int i = t; i < 4096; i += 256) {
            float bv = b2[i];
            #pragma unroll
            for (int j = 0; j < 15; ++j)
                acc[j] += bv * ((j < 3) ? Wc[i * 3 + j] : Wr[i * 12 + (j - 3)]);
        }
        const int lane = t & 63, wv = t >> 6;
        __shared__ float red[4][15];
        #pragma unroll
        for (int j = 0; j < 15; ++j) {
            float x = acc[j];
            #pragma unroll
            for (int off = 32; off >= 1; off >>= 1) x += __shfl_xor(x, off, 64);
            if (lane == 0) red[wv][j] = x;
        }
        __syncthreads();
        if (t < 15)
            bfv[t] = red[0][t] + red[1][t] + red[2][t] + red[3][t]
                   + ((t < 3) ? bc[t] : br[t - 3]);
    }
}

// ---------- 4. megaB: skinny W1 (1568 blocks, ky=8) ∥ pool (1024), 3:2 mix ----------
#define PB(NH, NW) { \
    uint2 v[NH * NW]; \
    _Pragma("unroll") for (int r = 0; r < NH; ++r) \
        _Pragma("unroll") for (int s = 0; s < NW; ++s) \
            v[r * NW + s] = *(const uint2*)(base + ho[r] + wo[s]); \
    float a0 = lo_f(v[0].x), a1 = hi_f(v[0].x); \
    float a2 = lo_f(v[0].y), a3 = hi_f(v[0].y); \
    _Pragma("unroll") for (int q = 1; q < NH * NW; ++q) { \
        a0 = fmaxf(a0, lo_f(v[q].x)); a1 = fmaxf(a1, hi_f(v[q].x)); \
        a2 = fmaxf(a2, lo_f(v[q].y)); a3 = fmaxf(a3, hi_f(v[q].y)); } \
    m0 = a0; m1 = a1; m2 = a2; m3 = a3; } break;

__global__ __launch_bounds__(512) void megaB(
        const unsigned short* __restrict__ fmT, const int* __restrict__ roi,
        unsigned short* __restrict__ pooled,
        const float* __restrict__ W1, const unsigned short* __restrict__ WfT,
        float* __restrict__ partial2) {
    const int g5 = blockIdx.x / 5, r5 = blockIdx.x % 5;
    const int t = threadIdx.x;
    if (r5 < 3) {
        // ---- skinny W1 block (NT stream) ----
        const int sb = g5 * 3 + r5;
        if (sb >= 1568) return;
        const int ky = sb / 196, bx = sb % 196;
        skinny_body<true>(W1, WfT, partial2, 25088, 512, bx, ky, t);
    } else {
        // ---- pool block (one ROI) ----
        const int n = g5 * 2 + (r5 - 3);
        if (n >= 1024) return;
        __shared__ int hoff[7][5], woff[7][5], hcnt[7], wcnt[7];
        if (t == 0) {
            int x0 = roi[n*4+0] / 16, y0 = roi[n*4+1] / 16;
            int x1 = roi[n*4+2] / 16, y1 = roi[n*4+3] / 16;
            if (x1 - x0 <= 1) { if (x1 < 84) x1 += 1; else x0 -= 1; }
            if (y1 - y0 <= 1) { if (y1 < 50) y1 += 1; else y0 -= 1; }
            int xs = min(max(x0, 0), 84), xe = min(max(x1, 0), 84);
            int ys = min(max(y0, 0), 50), ye = min(max(y1, 0), 50);
            int Lx = xe - xs, Ly = ye - ys;
            #pragma unroll
            for (int i = 0; i < 7; ++i) {
                int b0 = ys + (i * Ly) / 7, b1 = ys + ((i + 1) * Ly + 6) / 7;
                hcnt[i] = min(b1, b0 + 5) - b0;
                int c0 = xs + (i * Lx) / 7, c1 = xs + ((i + 1) * Lx + 6) / 7;
                wcnt[i] = min(c1, c0 + 5) - c0;
                #pragma unroll
                for (int q = 0; q < 5; ++q) {
                    hoff[i][q] = (b0 + q) * 43008;
                    woff[i][q] = (c0 + q) * 512;
                }
            }
        }
        __syncthreads();
        const int g = t >> 7;                 // 4 bin groups
        const int c4 = (t & 127) * 4;
        const unsigned short* base = fmT + c4;
        unsigned short* orow = pooled + (size_t)n * 25088;
        for (int bp = 0; bp < 13; ++bp) {
            int bin = bp * 4 + g;
            if (bin < 49) {
                int bi = bin / 7, bj = bin - bi * 7;
                int ho[5], wo[5];
                #pragma unroll
                for (int q = 0; q < 5; ++q) { ho[q] = hoff[bi][q]; wo[q] = woff[bj][q]; }
                int nh = hcnt[bi], nw = wcnt[bj];
                float m0, m1, m2, m3;
                switch ((nh - 1) * 5 + (nw - 1)) {
                    case  0: PB(1,1)  case  1: PB(1,2)  case  2: PB(1,3)
                    case  3: PB(1,4)  case  4: PB(1,5)
                    case  5: PB(2,1)  case  6: PB(2,2)  case  7: PB(2,3)
                    case  8: PB(2,4)  case  9: PB(2,5)
                    case 10: PB(3,1)  case 11: PB(3,2)  case 12: PB(3,3)
                    case 13: PB(3,4)  case 14: PB(3,5)
                    case 15: PB(4,1)  case 16: PB(4,2)  case 17: PB(4,3)
                    case 18: PB(4,4)  case 19: PB(4,5)
                    case 20: PB(5,1)  case 21: PB(5,2)  case 22: PB(5,3)
                    case 23: PB(5,4)  case 24: PB(5,5)
                    default: m0 = m1 = m2 = m3 = 0.f; break;
                }
                u16x4 o;
                o.x = f2bf(m0); o.y = f2bf(m1); o.z = f2bf(m2); o.w = f2bf(m3);
                __builtin_nontemporal_store(o, (u16x4*)(orow + bin * 512 + c4));
            }
        }
    }
}

// ---------- 5. reduce partial2 (r-order, 8 splits) -> WbigT bf16 (k'-permuted);
//             block 98 computes bbig ----------
__global__ __launch_bounds__(256) void reduce_wbig(
        const float* __restrict__ partial2, const float* __restrict__ Wf16,
        const float* __restrict__ bfv, const float* __restrict__ b1,
        unsigned short* __restrict__ WbigT, float* __restrict__ bbig) {
    const int t = threadIdx.x;
    if (blockIdx.x < 98) {
        const int r = blockIdx.x * 256 + t;      // W1 row (linear)
        float sj[16];
        #pragma unroll
        for (int j = 0; j < 16; ++j) sj[j] = 0.f;
        #pragma unroll
        for (int sp = 0; sp < 8; ++sp) {
            const float4* pp = (const float4*)(partial2 + ((size_t)sp * 25088 + r) * 16);
            float4 a = pp[0], b = pp[1], c = pp[2], d = pp[3];
            sj[0] += a.x; sj[1] += a.y; sj[2]  += a.z; sj[3]  += a.w;
            sj[4] += b.x; sj[5] += b.y; sj[6]  += b.z; sj[7]  += b.w;
            sj[8] += c.x; sj[9] += c.y; sj[10] += c.z; sj[11] += c.w;
            sj[12] += d.x; sj[13] += d.y; sj[14] += d.z; sj[15] += d.w;
        }
        const int c = r / 49, bin = r - c * 49;
        const int p = bin * 512 + c;             // k' index
        #pragma unroll
        for (int j = 0; j < 16; ++j)
            WbigT[(size_t)j * 25088 + p] = f2bf(sj[j]);
    } else {
        float acc[15];
        #pragma unroll
        for (int j = 0; j < 15; ++j) acc[j] = 0.f;
        for (int i = t; i < 4096; i += 256) {
            float bv = b1[i];
            #pragma unroll
            for (int j = 0; j < 15; ++j) acc[j] += bv * Wf16[i * 16 + j];
        }
        const int lane = t & 63, wv = t >> 6;
        __shared__ float red[4][15];
        #pragma unroll
        for (int j = 0; j < 15; ++j) {
            float x = acc[j];
            #pragma unroll
            for (int off = 32; off >= 1; off >>= 1) x += __shfl_xor(x, off, 64);
            if (lane == 0) red[wv][j] = x;
        }
        __syncthreads();
        if (t < 16) {
            float s = 0.f;
            if (t < 15)
                s = red[0][t] + red[1][t] + red[2][t] + red[3][t] + bfv[t];
            bbig[t] = s;
        }
    }
}

// ---------- 6. final GEMM: pooled @ WbigT^T -> partialG[8][1024][16] ----------
__global__ __launch_bounds__(256) void final_gemm(
        const unsigned short* __restrict__ pooled,
        const unsigned short* __restrict__ WbigT,
        float* __restrict__ partialG) {
    const int t = threadIdx.x, lane = t & 63, wave = t >> 6;
    const int m0 = blockIdx.x * 16, kz = blockIdx.y;
    const int lr = lane & 15, lks = lane >> 4;
    f32x4 acc = {0.f, 0.f, 0.f, 0.f};
    const unsigned short* arow = pooled + (size_t)(m0 + lr) * 25088 + kz * 3136 + lks * 8;
    const unsigned short* brow = WbigT + (size_t)lr * 25088 + kz * 3136 + lks * 8;
    for (int s = wave; s < 98; s += 4) {
        s16x8 a = __builtin_nontemporal_load((const s16x8*)(arow + s * 32));
        s16x8 b = *(const s16x8*)(brow + s * 32);
        acc = __builtin_amdgcn_mfma_f32_16x16x32_bf16(a, b, acc, 0, 0, 0);
    }
    __shared__ float red[4][64][4];
    #pragma unroll
    for (int r = 0; r < 4; ++r) red[wave][lane][r] = acc[r];
    __syncthreads();
    if (wave == 0) {
        #pragma unroll
        for (int r = 0; r < 4; ++r) {
            float s = red[0][lane][r] + red[1][lane][r] + red[2][lane][r] + red[3][lane][r];
            int row = m0 + (lane >> 4) * 4 + r;
            partialG[((size_t)kz * 1024 + row) * 16 + (lane & 15)] = s;
        }
    }
}

// ---------- 7. finalize: sum 8 partials + bbig, softmax(3), write out ----------
__global__ __launch_bounds__(256) void finalize_kernel(
        const float* __restrict__ partialG, const float* __restrict__ bbig,
        float* __restrict__ out) {
    const int m = blockIdx.x * 256 + threadIdx.x;   // 0..1023
    float v[15];
    #pragma unroll
    for (int j = 0; j < 15; ++j) v[j] = bbig[j];
    for (int kz = 0; kz < 8; ++kz) {
        const float* p = partialG + ((size_t)kz * 1024 + m) * 16;
        #pragma unroll
        for (int j = 0; j < 15; ++j) v[j] += p[j];
    }
    float mx = fmaxf(v[0], fmaxf(v[1], v[2]));
    float e0 = expf(v[0] - mx), e1 = expf(v[1] - mx), e2 = expf(v[2] - mx);
    float inv = 1.f / (e0 + e1 + e2);
    out[m * 3 + 0] = e0 * inv;
    out[m * 3 + 1] = e1 * inv;
    out[m * 3 + 2] = e2 * inv;
    #pragma unroll
    for (int j = 3; j < 15; ++j) out[3072 + m * 12 + (j - 3)] = v[j];
}

// ---------- launch ----------
extern "C" void kernel_launch(void* const* d_in, const int* in_sizes, int n_in,
                              void* d_out, int out_size, void* d_ws, size_t ws_size,
                              hipStream_t stream) {
    const float* featmap = (const float*)d_in[0];
    const int*   roi     = (const int*)d_in[1];
    const float* W1      = (const float*)d_in[2];
    const float* b1      = (const float*)d_in[3];
    const float* W2      = (const float*)d_in[4];
    const float* b2      = (const float*)d_in[5];
    const float* Wc      = (const float*)d_in[6];
    const float* bc      = (const float*)d_in[7];
    const float* Wr      = (const float*)d_in[8];
    const float* br      = (const float*)d_in[9];
    float* out = (float*)d_out;

    // workspace layout (bytes, 16-aligned)
    char* ws = (char*)d_ws;
    unsigned short* pooled   = (unsigned short*)(ws);                //  51,380,224  [1024][25088] bf16 (k')
    unsigned short* fmT      = (unsigned short*)(ws + 51380224);     //   4,300,800  [4200][512] bf16
    unsigned short* WcatT    = (unsigned short*)(ws + 55681024);     //     131,072  [16][4096] bf16
    unsigned short* WfT      = (unsigned short*)(ws + 55812096);     //     131,072  [16][4096] bf16
    float*          Wf16     = (float*)        (ws + 55943168);      //     262,144  [4096][16] f32
    float*          bfv      = (float*)        (ws + 56205312);      //          64
    float*          bbig     = (float*)        (ws + 56205376);      //          64  [16]
    float*          partial1 = (float*)        (ws + 56205440);      //   4,194,304  [8][4096][16] f32
    float*          partial2 = (float*)        (ws + 60399744);      //  51,380,224  [8][25088][16] f32 (r-order)
    unsigned short* WbigT    = (unsigned short*)(ws + 111779968);    //     802,816  [16][25088] bf16 (k'-order)
    float*          partialG = (float*)        (ws + 112582784);     //     524,288  [8][1024][16] f32

    prep_wcat<<<256, 256, 0, stream>>>(Wc, Wr, WcatT);
    prepA<<<1320, 512, 0, stream>>>(featmap, fmT, W2, WcatT, partial1);
    reduce_wf<<<257, 256, 0, stream>>>(partial1, b2, Wc, Wr, bc, br, Wf16, WfT, bfv);
    megaB<<<2615, 512, 0, stream>>>(fmT, roi, pooled, W1, WfT, partial2);
    reduce_wbig<<<99, 256, 0, stream>>>(partial2, Wf16, bfv, b1, WbigT, bbig);
    final_gemm<<<dim3(64, 8), 256, 0, stream>>>(pooled, WbigT, partialG);
    finalize_kernel<<<4, 256, 0, stream>>>(partialG, bbig, out);
}